// Round 9
// baseline (244.438 us; speedup 1.0000x reference)
//
#include <hip/hip_runtime.h>
#include <hip/hip_bf16.h>

#define T_WIN 336
#define T_OUT 48
#define T_S   168
#define BM    128
#define CH    782

typedef __attribute__((ext_vector_type(8))) short short8;
typedef __attribute__((ext_vector_type(4))) float f32x4;

__device__ __forceinline__ short f2bf(float f) {
    union { float f; unsigned u; } v; v.f = f;
    unsigned r = v.u + 0x7FFFu + ((v.u >> 16) & 1u);
    return (short)(r >> 16);
}

template <int CTRL, int RMASK>
__device__ __forceinline__ float dppf(float v) {
    union { float f; int i; } in, out;
    in.f = v;
    out.i = __builtin_amdgcn_update_dpp(0, in.i, CTRL, RMASK, 0xf, true);
    return out.f;
}

// write-through relaxed agent store: retires at MALL, does NOT dirty the local
// L2 -> keeps worker XCD L2s clean so the scan's release-publish wbl2 is cheap.
__device__ __forceinline__ void st_wt(float* p, float v) {
    __hip_atomic_store(p, v, __ATOMIC_RELAXED, __HIP_MEMORY_SCOPE_AGENT);
}
__device__ __forceinline__ void st_wt_u(unsigned* p, unsigned v) {
    __hip_atomic_store(p, v, __ATOMIC_RELAXED, __HIP_MEMORY_SCOPE_AGENT);
}

__global__ void init_flags(int* flags) {
    if (threadIdx.x < 3) flags[threadIdx.x * 32] = 0;
}

// ===================== fused persistent kernel =====================
// Round-18 (4th submit; rounds 6-8 were infra timeouts): direct-B GEMM.
// Round-5 falsified the scan-store theory (plain stores == write-through
// stores == 163 us); the residual is the gemm tile structure: 6 chunks x
// {stage 51KB -> vmcnt(0) -> barrier -> MFMA -> barrier} at 2 blocks/CU is
// latency-serial (~67us/round) while its MFMA content is ~1.2us. Fix: read B
// fragments DIRECTLY from W1F/W2F (L2-resident; packed layout makes per-lane
// addr = base + (kt*4+ct)*1024 + lane*16, byte-identical to the old LDS read)
// with a 1-deep prefetch pipeline. Deletes both per-chunk barriers + the
// vmcnt drain; chunk loop is barrier-free (hs is wave-local). LDS 74.7KB ->
// 23KB. Outputs (outp/lab/lpart) become write-through so worker L2s stay
// clean -> scan's 19 wbl2 publishes flush only its own ~16KB.
__global__ __launch_bounds__(256, 2) void fused_kernel(
    const float* __restrict__ x, const float* __restrict__ lvl_coef,
    const float* __restrict__ seas_coef, const float* __restrict__ seas_params,
    const float* __restrict__ W1, const float* __restrict__ W2,
    const float* __restrict__ b1, const float* __restrict__ b2,
    short* __restrict__ W1F, short* __restrict__ W2F,
    float* __restrict__ w_all, float* __restrict__ levels,
    float* __restrict__ cs, float* __restrict__ outp,
    float* __restrict__ lab, float* __restrict__ lpart,
    int* flags, int T, int N, int NB)
{
    __shared__ float Lsf[512];
    __shared__ __align__(16) short Lbf0[512];
    __shared__ __align__(16) short Lbf1[512];
    __shared__ float llv[BM];
    __shared__ __align__(16) short hs[BM * 72];   // 18432 B (loss1 aliases this)
    __shared__ int sh_tk;

    int blk = blockIdx.x;
    int tid = threadIdx.x;
    int* progress  = flags;       // groups published; 1000 = all done
    int* prep_done = flags + 32;  // +128B: prep blocks finished (target 302)
    int* ticket    = flags + 64;  // +256B: dynamic tile dispenser

    if (blk == 0) {
        // ---- serial ES scan (one wave, DPP affine scan, sync-free) ----
        if (tid >= 64) return;
        __builtin_amdgcn_s_setprio(3);
        int lane = tid;
        float a = 1.f / (1.f + __expf(-lvl_coef[0]));
        float g = 1.f / (1.f + __expf(-seas_coef[0]));
        float q = 1.f - a, gq = 1.f - g;

        for (int t = lane; t < T_S + 1; t += 64) w_all[t] = __expf(seas_params[t % T_S]);
        float lvl = x[0] / __expf(seas_params[0]);
        if (lane == 0) levels[0] = lvl;

        float wcur[3];
        #pragma unroll
        for (int i = 0; i < 3; ++i)
            wcur[i] = __expf(seas_params[(1 + 3 * lane + i) % T_S]);

        float f1 = q * q * q;
        float f2 = f1 * f1, f4 = f2 * f2, f8 = f4 * f4;
        float lnq = __logf(q);
        float P15 = __expf(3.f * (float)((lane & 15) + 1) * lnq);
        float P31 = __expf(3.f * (float)((lane & 31) + 1) * lnq);
        float pw3l = __expf(3.f * (float)lane * lnq);

        int j0 = 3 * lane;

        auto do_chunk = [&](const float* xvv, float* lev) {
            float rr[3];
            #pragma unroll
            for (int i = 0; i < 3; ++i) rr[i] = a * xvv[i] * __builtin_amdgcn_rcpf(wcur[i]);
            float S = fmaf(q, fmaf(q, rr[0], rr[1]), rr[2]);
            S = fmaf(f1, dppf<0x111, 0xf>(S), S);   // row_shr:1
            S = fmaf(f2, dppf<0x112, 0xf>(S), S);   // row_shr:2
            S = fmaf(f4, dppf<0x114, 0xf>(S), S);   // row_shr:4
            S = fmaf(f8, dppf<0x118, 0xf>(S), S);   // row_shr:8
            S = fmaf(P15, dppf<0x142, 0xa>(S), S);  // row_bcast:15 -> rows 1,3
            S = fmaf(P31, dppf<0x143, 0xc>(S), S);  // row_bcast:31 -> rows 2,3
            float E = dppf<0x138, 0xf>(S);          // wave_shr:1 (exclusive)
            float lv = fmaf(pw3l, lvl, E);
            #pragma unroll
            for (int i = 0; i < 3; ++i) { lv = fmaf(q, lv, rr[i]); lev[i] = lv; }
            { union { float f; int i; } uu; uu.i = __builtin_amdgcn_readlane(__builtin_bit_cast(int, lev[2]), 55); lvl = uu.f; }
            #pragma unroll
            for (int i = 0; i < 3; ++i)
                wcur[i] = fmaf(gq, wcur[i], g * xvv[i] * __builtin_amdgcn_rcpf(lev[i]));
        };

        // depth-2 group prefetch pipeline
        float xg[4][3], xh[4][3], x2[4][3];
        #pragma unroll
        for (int u = 0; u < 4; ++u)
            #pragma unroll
            for (int i = 0; i < 3; ++i) {
                xg[u][i] = x[1 + T_S * u + j0 + i];
                xh[u][i] = x[1 + T_S * (4 + u) + j0 + i];
            }

        const float* px = x + 1 + 8 * T_S + j0;
        float* pl = levels + 1 + j0;
        float* pw = w_all + 1 + T_S + j0;

        for (int grp = 0; grp < 148; ++grp) {
            // publish: RELEASE agent store (vmcnt drain + wbl2 + store). With
            // worker outputs write-through, this XCD's dirty set is only the
            // scan's own ~16KB -> sub-us flush.
            if (grp && (grp & 7) == 0 && lane == 0)
                __hip_atomic_store(progress, grp, __ATOMIC_RELEASE, __HIP_MEMORY_SCOPE_AGENT);

            if (grp < 146) {
                #pragma unroll
                for (int u = 0; u < 4; ++u)
                    #pragma unroll
                    for (int i = 0; i < 3; ++i)
                        x2[u][i] = px[u * T_S + i];
            } else {
                #pragma unroll
                for (int u = 0; u < 4; ++u)
                    #pragma unroll
                    for (int i = 0; i < 3; ++i) {
                        int t = 1 + T_S * (4 * (grp + 2) + u) + j0 + i;
                        x2[u][i] = x[min(t, T - 1)];
                    }
            }
            px += 4 * T_S;

            #pragma unroll
            for (int u = 0; u < 4; ++u) {
                float lev[3];
                do_chunk(xg[u], lev);
                #pragma unroll
                for (int i = 0; i < 3; ++i) {
                    pl[u * T_S + i] = lev[i];
                    pw[u * T_S + i] = wcur[i];
                }
            }
            pl += 4 * T_S; pw += 4 * T_S;
            #pragma unroll
            for (int u = 0; u < 4; ++u)
                #pragma unroll
                for (int i = 0; i < 3; ++i) { xg[u][i] = xh[u][i]; xh[u][i] = x2[u][i]; }
        }

        // tail: chunks 592..595, guarded stores
        #pragma unroll
        for (int u = 0; u < 4; ++u) {
            int c = 592 + u;
            if (c * T_S >= T - 1) break;
            int len = (T - 1) - T_S * c; if (len > T_S) len = T_S;
            float lev[3];
            do_chunk(xg[u], lev);
            #pragma unroll
            for (int i = 0; i < 3; ++i) {
                if (j0 + i < len) {
                    pl[u * T_S + i] = lev[i];
                    pw[u * T_S + i] = wcur[i];
                }
            }
        }
        if (lane == 0)
            __hip_atomic_store(progress, 1000, __ATOMIC_RELEASE, __HIP_MEMORY_SCOPE_AGENT);
        return;
    }

    if (blk <= 302) {
        if (blk >= 301) {              // ---- cs: colsum of W1 ----
            int k = (blk - 301) * 256 + tid;
            if (k < T_WIN) {
                float s = 0.f;
                for (int j = 0; j < T_WIN; ++j) s += W1[j * T_WIN + k];
                st_wt(&cs[k], s);
            }
        } else if (blk >= 265) {       // ---- W2F ----
            int d = (blk - 265) * 256 + tid;
            int j2 = d & 3, lane = (d >> 2) & 63, f = d >> 8;
            int ct2 = f % 3, rest = f / 3;
            int kt2 = rest & 1, c = rest >> 1;
            int k = c * 64 + kt2 * 32 + (lane >> 4) * 8 + 2 * j2;
            int o = ct2 * 16 + (lane & 15);
            unsigned short lo = 0, hi = 0;
            if (k     < T_WIN) lo = (unsigned short)f2bf(W2[k * T_OUT + o]);
            if (k + 1 < T_WIN) hi = (unsigned short)f2bf(W2[(k + 1) * T_OUT + o]);
            st_wt_u(&((unsigned*)W2F)[d], ((unsigned)hi << 16) | (unsigned)lo);
        } else {                       // ---- W1F ----
            int d = (blk - 1) * 256 + tid;
            int j2 = d & 3, lane = (d >> 2) & 63, f = d >> 8;
            int ct = f & 3, rest = f >> 2;
            int kt = rest % 11, c = rest / 11;
            int k = kt * 32 + (lane >> 4) * 8 + 2 * j2;
            int col = c * 64 + ct * 16 + (lane & 15);
            unsigned short lo = 0, hi = 0;
            if (col < T_WIN) {
                if (k     < T_WIN) lo = (unsigned short)f2bf(W1[k * T_WIN + col]);
                if (k + 1 < T_WIN) hi = (unsigned short)f2bf(W1[(k + 1) * T_WIN + col]);
            }
            st_wt_u(&((unsigned*)W1F)[d], ((unsigned)hi << 16) | (unsigned)lo);
        }
        __syncthreads();   // per-wave vmcnt drained before s_barrier
        if (tid == 0)
            __hip_atomic_fetch_add(prep_done, 1, __ATOMIC_RELAXED, __HIP_MEMORY_SCOPE_AGENT);
        // fall through to worker loop
    }

    // ================= worker loop (blocks 1..511) =================
    if (tid < 64) {
        while (__hip_atomic_load(prep_done, __ATOMIC_RELAXED, __HIP_MEMORY_SCOPE_AGENT) < 302)
            __builtin_amdgcn_s_sleep(16);
    }
    __syncthreads();   // W1F/W2F/cs at MALL; never stale-cached here (idempotent data)

    int lane = tid & 63, wv = tid >> 6;
    int lr = lane & 15, lq = lane >> 4;
    int rw = wv * 32;
    int last_seen = 0;
    int NT = NB + 128;

    for (;;) {
        __syncthreads();   // prior tile's LDS consumers done; sh_tk reusable
        if (tid == 0) sh_tk = atomicAdd(ticket, 1);
        __syncthreads();
        int tk = sh_tk;
        if (tk >= NT) return;

        // ---- ticket -> tile: interleave loss1 tiles 1-in-7 ----
        int sev = tk / 7;
        bool isl = (tk % 7 == 6) && (sev < 128);
        int tile = isl ? (NB + sev) : (tk - min(sev, 128));

        // ---- wait for scan frontier (+128-float pad for line tails) ----
        int need_t = (tile < NB) ? (tile * BM + 512 + 128)
                                 : ((tile - NB) * CH + CH + 2 + 128);
        if (need_t > T) need_t = T;
        int req = (need_t + 670) / 672;
        if (last_seen < req) {
            if (tid < 64) {
                while (__hip_atomic_load(progress, __ATOMIC_RELAXED, __HIP_MEMORY_SCOPE_AGENT) < req)
                    __builtin_amdgcn_s_sleep(32);
            }
            __syncthreads();
            last_seen = req;
        }

        if (tile >= NB) {
            // ---------------- loss1 tile ----------------
            float* ls  = (float*)hs;
            float* red = (float*)(hs + 4096);
            int lb = tile - NB;
            int lo = lb * CH;
            int n = T - lo; if (n > CH + 2) n = CH + 2;
            for (int i = tid; i < n; i += 256) ls[i] = __logf(levels[lo + i]);
            __syncthreads();
            float s = 0.f;
            int dmax = (T - 2) - lo; if (dmax > CH) dmax = CH;
            for (int i = tid; i < dmax; i += 256) {
                float d = ls[i + 2] - 2.f * ls[i + 1] + ls[i];
                s = fmaf(d, d, s);
            }
            red[tid] = s;
            __syncthreads();
            for (int w = 128; w > 0; w >>= 1) {
                if (tid < w) red[tid] += red[tid + w];
                __syncthreads();
            }
            if (tid == 0) st_wt(&lpart[lb], red[0]);
            continue;
        }

        // ---------------- gemm tile (barrier-free chunk loop) ----------------
        int n0 = tile * BM;
        float C = __logf(levels[min(n0 + T_WIN, T - 1)]);

        for (int i = tid; i < 512; i += 256) {
            int t = n0 + i;
            float v = (t < T) ? (__logf(x[t]) - __logf(w_all[t]) - C) : 0.f;
            Lsf[i] = v;
            Lbf0[i] = f2bf(v);
        }
        for (int i = tid; i < BM; i += 256) {
            int t = n0 + i + T_WIN;
            llv[i] = (t < T) ? (__logf(levels[t]) - C) : 0.f;
        }
        __syncthreads();
        for (int i = tid; i < 512; i += 256) Lbf1[i] = (i < 511) ? Lbf0[i + 1] : (short)0;
        __syncthreads();

        // pack 22 A-fragments (parity arrays: 4B-aligned b32 reads)
        const short* abase = ((lr & 1) ? Lbf1 : Lbf0) + rw + (lr & ~1);
        short8 af[11][2];
        #pragma unroll
        for (int kt = 0; kt < 11; ++kt) {
            #pragma unroll
            for (int mt = 0; mt < 2; ++mt) {
                const int* ip = (const int*)(abase + mt * 16 + kt * 32 + lq * 8);
                union { short8 s; int i[4]; } u;
                u.i[0] = ip[0]; u.i[1] = ip[1]; u.i[2] = ip[2]; u.i[3] = ip[3];
                af[kt][mt] = u.s;
            }
        }

        f32x4 zero4 = {0.f, 0.f, 0.f, 0.f};
        f32x4 acc2[2][3];
        #pragma unroll
        for (int mt = 0; mt < 2; ++mt)
            #pragma unroll
            for (int ct = 0; ct < 3; ++ct) acc2[mt][ct] = zero4;

        #pragma unroll 1
        for (int c = 0; c < 6; ++c) {
            // per-lane B addresses: byte-identical to the old LDS-staged reads
            const char* g1 = (const char*)(W1F + (size_t)c * 11 * 4 * 512) + lane * 16;
            const char* g2 = (const char*)(W2F + (size_t)c * 6 * 512) + lane * 16;

            float b1v[4], csv[4];
            #pragma unroll
            for (int ct = 0; ct < 4; ++ct) {
                int col = c * 64 + ct * 16 + lr;
                b1v[ct] = (col < T_WIN) ? b1[col] : 0.f;
                csv[ct] = (col < T_WIN) ? cs[col] : 0.f;
            }

            f32x4 acc1[2][4];
            #pragma unroll
            for (int mt = 0; mt < 2; ++mt)
                #pragma unroll
                for (int ct = 0; ct < 4; ++ct) acc1[mt][ct] = zero4;

            // GEMM1: direct-B with 1-deep prefetch pipeline
            short8 bcur[4], bnxt[4];
            #pragma unroll
            for (int ct = 0; ct < 4; ++ct)
                bcur[ct] = *(const short8*)(g1 + ct * 1024);
            #pragma unroll
            for (int kt = 0; kt < 11; ++kt) {
                if (kt < 10) {
                    #pragma unroll
                    for (int ct = 0; ct < 4; ++ct)
                        bnxt[ct] = *(const short8*)(g1 + ((kt + 1) * 4 + ct) * 1024);
                }
                #pragma unroll
                for (int ct = 0; ct < 4; ++ct) {
                    acc1[0][ct] = __builtin_amdgcn_mfma_f32_16x16x32_bf16(af[kt][0], bcur[ct], acc1[0][ct], 0, 0, 0);
                    acc1[1][ct] = __builtin_amdgcn_mfma_f32_16x16x32_bf16(af[kt][1], bcur[ct], acc1[1][ct], 0, 0, 0);
                }
                #pragma unroll
                for (int ct = 0; ct < 4; ++ct) bcur[ct] = bnxt[ct];
            }

            // epilogue -> hs (wave-local rows; no barrier needed)
            #pragma unroll
            for (int mt = 0; mt < 2; ++mt)
                #pragma unroll
                for (int ct = 0; ct < 4; ++ct)
                    #pragma unroll
                    for (int r = 0; r < 4; ++r) {
                        int row = rw + mt * 16 + lq * 4 + r;
                        float pre = acc1[mt][ct][r] + b1v[ct] - llv[row] * csv[ct];
                        float e = __expf(2.f * pre);
                        float h = 1.f - 2.f * __builtin_amdgcn_rcpf(e + 1.f);
                        hs[row * 72 + ct * 16 + lr] = f2bf(h);
                    }

            // GEMM2: direct-B
            #pragma unroll
            for (int kt2 = 0; kt2 < 2; ++kt2) {
                short8 a2[2];
                #pragma unroll
                for (int mt = 0; mt < 2; ++mt)
                    a2[mt] = *(const short8*)&hs[(rw + mt * 16 + lr) * 72 + kt2 * 32 + lq * 8];
                #pragma unroll
                for (int ct2 = 0; ct2 < 3; ++ct2) {
                    short8 bf2 = *(const short8*)(g2 + (kt2 * 3 + ct2) * 1024);
                    acc2[0][ct2] = __builtin_amdgcn_mfma_f32_16x16x32_bf16(a2[0], bf2, acc2[0][ct2], 0, 0, 0);
                    acc2[1][ct2] = __builtin_amdgcn_mfma_f32_16x16x32_bf16(a2[1], bf2, acc2[1][ct2], 0, 0, 0);
                }
            }
        }

        // labels (write-through; Lsf/llv still valid — chunk loop never touches them)
        for (int u2 = tid; u2 < BM * T_OUT; u2 += 256) {
            int row = u2 / T_OUT, j = u2 - row * T_OUT;
            int nn = n0 + row;
            if (nn < N) st_wt(&lab[(size_t)nn * T_OUT + j], Lsf[row + T_WIN + j] - llv[row]);
        }

        float b2v[3];
        #pragma unroll
        for (int ct2 = 0; ct2 < 3; ++ct2) b2v[ct2] = b2[ct2 * 16 + lr];
        #pragma unroll
        for (int mt = 0; mt < 2; ++mt)
            #pragma unroll
            for (int ct2 = 0; ct2 < 3; ++ct2)
                #pragma unroll
                for (int r = 0; r < 4; ++r) {
                    int row = n0 + rw + mt * 16 + lq * 4 + r;
                    if (row < N)
                        st_wt(&outp[(size_t)row * T_OUT + ct2 * 16 + lr], acc2[mt][ct2][r] + b2v[ct2]);
                }
    }
}

__global__ __launch_bounds__(128) void loss2_kernel(
    const float* __restrict__ part, const int* __restrict__ lvp,
    float* __restrict__ out_loss, int T)
{
    __shared__ float red[128];
    red[threadIdx.x] = part[threadIdx.x];
    __syncthreads();
    for (int w = 64; w > 0; w >>= 1) {
        if (threadIdx.x < (unsigned)w) red[threadIdx.x] += red[threadIdx.x + w];
        __syncthreads();
    }
    if (threadIdx.x == 0) out_loss[0] = red[0] * (float)lvp[0] / (float)(T - 2);
}

extern "C" void kernel_launch(void* const* d_in, const int* in_sizes, int n_in,
                              void* d_out, int out_size, void* d_ws, size_t ws_size,
                              hipStream_t stream) {
    const float* x    = (const float*)d_in[0];
    const float* lvlc = (const float*)d_in[1];
    const float* seac = (const float*)d_in[2];
    const float* sp   = (const float*)d_in[3];
    const float* W1   = (const float*)d_in[4];
    const float* b1   = (const float*)d_in[5];
    const float* W2   = (const float*)d_in[6];
    const float* b2   = (const float*)d_in[7];
    const int*   lvp  = (const int*)d_in[10];

    int T = in_sizes[0];
    int N = T - T_WIN - T_OUT + 1;
    int NB = (N + BM - 1) / BM;

    short* W1F    = (short*)d_ws;                  // 264*512 shorts
    short* W2F    = W1F + 264 * 512;               // 36*512 shorts
    float* w_all  = (float*)(W2F + 36 * 512);      // T + 192
    float* levels = w_all + T + 192;               // T
    float* cs     = levels + T;                    // 352
    float* lpart  = cs + 352;                      // 128
    int*   flagsp = (int*)(lpart + 128);           // 3 flags on separate 128B lines

    float* outp  = (float*)d_out;
    float* lab   = outp + (size_t)N * T_OUT;
    float* lossp = lab + (size_t)N * T_OUT;

    init_flags<<<1, 64, 0, stream>>>(flagsp);
    fused_kernel<<<512, 256, 0, stream>>>(x, lvlc, seac, sp, W1, W2, b1, b2,
                                          W1F, W2F, w_all, levels, cs,
                                          outp, lab, lpart, flagsp, T, N, NB);
    loss2_kernel<<<1, 128, 0, stream>>>(lpart, lvp, lossp, T);
}

// Round 10
// 221.492 us; speedup vs baseline: 1.1036x; 1.1036x over previous
//
#include <hip/hip_runtime.h>
#include <hip/hip_bf16.h>

#define T_WIN 336
#define T_OUT 48
#define T_S   168
#define BM    128
#define CH    782

typedef __attribute__((ext_vector_type(8))) short short8;
typedef __attribute__((ext_vector_type(4))) float f32x4;

__device__ __forceinline__ short f2bf(float f) {
    union { float f; unsigned u; } v; v.f = f;
    unsigned r = v.u + 0x7FFFu + ((v.u >> 16) & 1u);
    return (short)(r >> 16);
}

template <int CTRL, int RMASK>
__device__ __forceinline__ float dppf(float v) {
    union { float f; int i; } in, out;
    in.f = v;
    out.i = __builtin_amdgcn_update_dpp(0, in.i, CTRL, RMASK, 0xf, true);
    return out.f;
}

// write-through relaxed agent store (prep outputs only; off critical path)
__device__ __forceinline__ void st_wt(float* p, float v) {
    __hip_atomic_store(p, v, __ATOMIC_RELAXED, __HIP_MEMORY_SCOPE_AGENT);
}
__device__ __forceinline__ void st_wt_u(unsigned* p, unsigned v) {
    __hip_atomic_store(p, v, __ATOMIC_RELAXED, __HIP_MEMORY_SCOPE_AGENT);
}

// CU identity: HW_ID bits [15:8] = CU_ID|SH_ID|SE_ID (gfx9 layout) + XCC_ID.
// Wrong decode is SAFE: cuid mismatch -> nobody parks -> round-5 behavior.
__device__ __forceinline__ int my_cu_id() {
    unsigned hwid = __builtin_amdgcn_s_getreg((15 << 11) | (0 << 6) | 4);   // HW_REG_HW_ID, 16b
    unsigned xcc  = __builtin_amdgcn_s_getreg((3 << 11) | (0 << 6) | 20);   // HW_REG_XCC_ID, 4b
    return (int)(((hwid >> 8) & 0xFFu) | (xcc << 8)) + 1;                   // +1: 0 = "unset"
}

__global__ void init_flags(int* flags) {
    if (threadIdx.x < 4) flags[threadIdx.x * 32] = 0;
}

// ===================== fused persistent kernel =====================
// Round-19: private-CU scan test. Evidence: r2 (wt-stores)=163.7, r5 (plain
// stores+release)=163.2, r9 (direct-B gemm)=177 — scan-store mechanism AND
// gemm structure both falsified as limiters; total ≈ scan-under-load + ~5us,
// so the scan runs ~160us co-resident vs 91us standalone (1.8x stretch).
// Suspect: CU co-residency (worker block's trans-heavy staging/epilogue
// contends with the scan chain's 6 rcp/chunk + DPPs; setprio can't preempt
// in-flight wave64 trans ops). Single change vs round-5 (best measured):
// block 0 publishes its CU id; the one worker block sharing that CU parks
// (s_sleep poll) until the scan completes, then joins the drain. Cost 0.4%
// of workers; wrong-id fallback = exact round-5 behavior.
__global__ __launch_bounds__(256, 2) void fused_kernel(
    const float* __restrict__ x, const float* __restrict__ lvl_coef,
    const float* __restrict__ seas_coef, const float* __restrict__ seas_params,
    const float* __restrict__ W1, const float* __restrict__ W2,
    const float* __restrict__ b1, const float* __restrict__ b2,
    short* __restrict__ W1F, short* __restrict__ W2F,
    float* __restrict__ w_all, float* __restrict__ levels,
    float* __restrict__ cs, float* __restrict__ outp,
    float* __restrict__ lab, float* __restrict__ lpart,
    int* flags, int T, int N, int NB)
{
    __shared__ float Lsf[512];
    __shared__ __align__(16) short Lbf0[512];
    __shared__ __align__(16) short Lbf1[512];
    __shared__ float llv[BM];
    __shared__ __align__(16) short hs[BM * 72];       // 18432 B (loss1 aliases this)
    __shared__ __align__(16) short B1s[11 * 4 * 512]; // 45056 B
    __shared__ __align__(16) short B2s[6 * 512];      // 6144 B
    __shared__ int sh_tk;

    int blk = blockIdx.x;
    int tid = threadIdx.x;
    int* progress  = flags;       // groups published; 1000 = all done
    int* prep_done = flags + 32;  // +128B: prep blocks finished (target 302)
    int* ticket    = flags + 64;  // +256B: dynamic tile dispenser
    int* scan_cu   = flags + 96;  // +384B: scan block's CU identity (+1)

    if (blk == 0) {
        // ---- serial ES scan (one wave, DPP affine scan, sync-free) ----
        if (tid >= 64) return;
        __builtin_amdgcn_s_setprio(3);
        int lane = tid;
        if (lane == 0)
            __hip_atomic_store(scan_cu, my_cu_id(), __ATOMIC_RELAXED, __HIP_MEMORY_SCOPE_AGENT);
        float a = 1.f / (1.f + __expf(-lvl_coef[0]));
        float g = 1.f / (1.f + __expf(-seas_coef[0]));
        float q = 1.f - a, gq = 1.f - g;

        for (int t = lane; t < T_S + 1; t += 64) w_all[t] = __expf(seas_params[t % T_S]);
        float lvl = x[0] / __expf(seas_params[0]);
        if (lane == 0) levels[0] = lvl;

        float wcur[3];
        #pragma unroll
        for (int i = 0; i < 3; ++i)
            wcur[i] = __expf(seas_params[(1 + 3 * lane + i) % T_S]);

        float f1 = q * q * q;
        float f2 = f1 * f1, f4 = f2 * f2, f8 = f4 * f4;
        float lnq = __logf(q);
        float P15 = __expf(3.f * (float)((lane & 15) + 1) * lnq);
        float P31 = __expf(3.f * (float)((lane & 31) + 1) * lnq);
        float pw3l = __expf(3.f * (float)lane * lnq);

        int j0 = 3 * lane;

        auto do_chunk = [&](const float* xvv, float* lev) {
            float rr[3];
            #pragma unroll
            for (int i = 0; i < 3; ++i) rr[i] = a * xvv[i] * __builtin_amdgcn_rcpf(wcur[i]);
            float S = fmaf(q, fmaf(q, rr[0], rr[1]), rr[2]);
            S = fmaf(f1, dppf<0x111, 0xf>(S), S);   // row_shr:1
            S = fmaf(f2, dppf<0x112, 0xf>(S), S);   // row_shr:2
            S = fmaf(f4, dppf<0x114, 0xf>(S), S);   // row_shr:4
            S = fmaf(f8, dppf<0x118, 0xf>(S), S);   // row_shr:8
            S = fmaf(P15, dppf<0x142, 0xa>(S), S);  // row_bcast:15 -> rows 1,3
            S = fmaf(P31, dppf<0x143, 0xc>(S), S);  // row_bcast:31 -> rows 2,3
            float E = dppf<0x138, 0xf>(S);          // wave_shr:1 (exclusive)
            float lv = fmaf(pw3l, lvl, E);
            #pragma unroll
            for (int i = 0; i < 3; ++i) { lv = fmaf(q, lv, rr[i]); lev[i] = lv; }
            { union { float f; int i; } uu; uu.i = __builtin_amdgcn_readlane(__builtin_bit_cast(int, lev[2]), 55); lvl = uu.f; }
            #pragma unroll
            for (int i = 0; i < 3; ++i)
                wcur[i] = fmaf(gq, wcur[i], g * xvv[i] * __builtin_amdgcn_rcpf(lev[i]));
        };

        // depth-2 group prefetch pipeline
        float xg[4][3], xh[4][3], x2[4][3];
        #pragma unroll
        for (int u = 0; u < 4; ++u)
            #pragma unroll
            for (int i = 0; i < 3; ++i) {
                xg[u][i] = x[1 + T_S * u + j0 + i];
                xh[u][i] = x[1 + T_S * (4 + u) + j0 + i];
            }

        const float* px = x + 1 + 8 * T_S + j0;
        float* pl = levels + 1 + j0;
        float* pw = w_all + 1 + T_S + j0;

        for (int grp = 0; grp < 148; ++grp) {
            // publish: RELEASE agent store (vmcnt drain + wbl2 + store)
            if (grp && (grp & 7) == 0 && lane == 0)
                __hip_atomic_store(progress, grp, __ATOMIC_RELEASE, __HIP_MEMORY_SCOPE_AGENT);

            if (grp < 146) {
                #pragma unroll
                for (int u = 0; u < 4; ++u)
                    #pragma unroll
                    for (int i = 0; i < 3; ++i)
                        x2[u][i] = px[u * T_S + i];
            } else {
                #pragma unroll
                for (int u = 0; u < 4; ++u)
                    #pragma unroll
                    for (int i = 0; i < 3; ++i) {
                        int t = 1 + T_S * (4 * (grp + 2) + u) + j0 + i;
                        x2[u][i] = x[min(t, T - 1)];
                    }
            }
            px += 4 * T_S;

            #pragma unroll
            for (int u = 0; u < 4; ++u) {
                float lev[3];
                do_chunk(xg[u], lev);
                #pragma unroll
                for (int i = 0; i < 3; ++i) {
                    pl[u * T_S + i] = lev[i];
                    pw[u * T_S + i] = wcur[i];
                }
            }
            pl += 4 * T_S; pw += 4 * T_S;
            #pragma unroll
            for (int u = 0; u < 4; ++u)
                #pragma unroll
                for (int i = 0; i < 3; ++i) { xg[u][i] = xh[u][i]; xh[u][i] = x2[u][i]; }
        }

        // tail: chunks 592..595, guarded stores
        #pragma unroll
        for (int u = 0; u < 4; ++u) {
            int c = 592 + u;
            if (c * T_S >= T - 1) break;
            int len = (T - 1) - T_S * c; if (len > T_S) len = T_S;
            float lev[3];
            do_chunk(xg[u], lev);
            #pragma unroll
            for (int i = 0; i < 3; ++i) {
                if (j0 + i < len) {
                    pl[u * T_S + i] = lev[i];
                    pw[u * T_S + i] = wcur[i];
                }
            }
        }
        if (lane == 0)
            __hip_atomic_store(progress, 1000, __ATOMIC_RELEASE, __HIP_MEMORY_SCOPE_AGENT);
        return;
    }

    if (blk <= 302) {
        if (blk >= 301) {              // ---- cs: colsum of W1 ----
            int k = (blk - 301) * 256 + tid;
            if (k < T_WIN) {
                float s = 0.f;
                for (int j = 0; j < T_WIN; ++j) s += W1[j * T_WIN + k];
                st_wt(&cs[k], s);
            }
        } else if (blk >= 265) {       // ---- W2F ----
            int d = (blk - 265) * 256 + tid;
            int j2 = d & 3, lane = (d >> 2) & 63, f = d >> 8;
            int ct2 = f % 3, rest = f / 3;
            int kt2 = rest & 1, c = rest >> 1;
            int k = c * 64 + kt2 * 32 + (lane >> 4) * 8 + 2 * j2;
            int o = ct2 * 16 + (lane & 15);
            unsigned short lo = 0, hi = 0;
            if (k     < T_WIN) lo = (unsigned short)f2bf(W2[k * T_OUT + o]);
            if (k + 1 < T_WIN) hi = (unsigned short)f2bf(W2[(k + 1) * T_OUT + o]);
            st_wt_u(&((unsigned*)W2F)[d], ((unsigned)hi << 16) | (unsigned)lo);
        } else {                       // ---- W1F ----
            int d = (blk - 1) * 256 + tid;
            int j2 = d & 3, lane = (d >> 2) & 63, f = d >> 8;
            int ct = f & 3, rest = f >> 2;
            int kt = rest % 11, c = rest / 11;
            int k = kt * 32 + (lane >> 4) * 8 + 2 * j2;
            int col = c * 64 + ct * 16 + (lane & 15);
            unsigned short lo = 0, hi = 0;
            if (col < T_WIN) {
                if (k     < T_WIN) lo = (unsigned short)f2bf(W1[k * T_WIN + col]);
                if (k + 1 < T_WIN) hi = (unsigned short)f2bf(W1[(k + 1) * T_WIN + col]);
            }
            st_wt_u(&((unsigned*)W1F)[d], ((unsigned)hi << 16) | (unsigned)lo);
        }
        __syncthreads();   // per-wave vmcnt drained before s_barrier
        if (tid == 0)
            __hip_atomic_fetch_add(prep_done, 1, __ATOMIC_RELAXED, __HIP_MEMORY_SCOPE_AGENT);
        // fall through to worker loop
    }

    // ================= worker loop (blocks 1..511) =================
    if (tid < 64) {
        while (__hip_atomic_load(prep_done, __ATOMIC_RELAXED, __HIP_MEMORY_SCOPE_AGENT) < 302)
            __builtin_amdgcn_s_sleep(16);
    }
    __syncthreads();   // W1F/W2F/cs at MALL; never stale-cached here

    int lane = tid & 63, wv = tid >> 6;
    int lr = lane & 15, lq = lane >> 4;
    int rw = wv * 32;
    int last_seen = 0;
    int NT = NB + 128;

    // ---- Round-19: park if this block shares the scan's CU ----
    {
        int mine = my_cu_id();
        if (__hip_atomic_load(scan_cu, __ATOMIC_RELAXED, __HIP_MEMORY_SCOPE_AGENT) == mine) {
            while (__hip_atomic_load(progress, __ATOMIC_RELAXED, __HIP_MEMORY_SCOPE_AGENT) < 1000)
                __builtin_amdgcn_s_sleep(64);
            last_seen = 1000;
        }
    }

    for (;;) {
        __syncthreads();   // prior tile's LDS consumers done; sh_tk reusable
        if (tid == 0) sh_tk = atomicAdd(ticket, 1);
        __syncthreads();
        int tk = sh_tk;
        if (tk >= NT) return;

        // ---- ticket -> tile: interleave loss1 tiles 1-in-7 ----
        int sev = tk / 7;
        bool isl = (tk % 7 == 6) && (sev < 128);
        int tile = isl ? (NB + sev) : (tk - min(sev, 128));

        // ---- wait for scan frontier (+128-float pad for line tails) ----
        int need_t = (tile < NB) ? (tile * BM + 512 + 128)
                                 : ((tile - NB) * CH + CH + 2 + 128);
        if (need_t > T) need_t = T;
        int req = (need_t + 670) / 672;
        if (last_seen < req) {
            if (tid < 64) {
                while (__hip_atomic_load(progress, __ATOMIC_RELAXED, __HIP_MEMORY_SCOPE_AGENT) < req)
                    __builtin_amdgcn_s_sleep(32);
            }
            __syncthreads();
            last_seen = req;
        }

        if (tile >= NB) {
            // ---------------- loss1 tile ----------------
            float* ls  = (float*)hs;
            float* red = (float*)(hs + 4096);
            int lb = tile - NB;
            int lo = lb * CH;
            int n = T - lo; if (n > CH + 2) n = CH + 2;
            for (int i = tid; i < n; i += 256) ls[i] = __logf(levels[lo + i]);
            __syncthreads();
            float s = 0.f;
            int dmax = (T - 2) - lo; if (dmax > CH) dmax = CH;
            for (int i = tid; i < dmax; i += 256) {
                float d = ls[i + 2] - 2.f * ls[i + 1] + ls[i];
                s = fmaf(d, d, s);
            }
            red[tid] = s;
            __syncthreads();
            for (int w = 128; w > 0; w >>= 1) {
                if (tid < w) red[tid] += red[tid + w];
                __syncthreads();
            }
            if (tid == 0) lpart[lb] = red[0];
            continue;
        }

        // ---------------- gemm tile ----------------
        int n0 = tile * BM;
        float C = __logf(levels[min(n0 + T_WIN, T - 1)]);

        for (int i = tid; i < 512; i += 256) {
            int t = n0 + i;
            float v = (t < T) ? (__logf(x[t]) - __logf(w_all[t]) - C) : 0.f;
            Lsf[i] = v;
            Lbf0[i] = f2bf(v);
        }
        for (int i = tid; i < BM; i += 256) {
            int t = n0 + i + T_WIN;
            llv[i] = (t < T) ? (__logf(levels[t]) - C) : 0.f;
        }
        __syncthreads();
        for (int i = tid; i < 512; i += 256) Lbf1[i] = (i < 511) ? Lbf0[i + 1] : (short)0;
        __syncthreads();

        for (int u2 = tid; u2 < BM * T_OUT; u2 += 256) {
            int row = u2 / T_OUT, j = u2 - row * T_OUT;
            int nn = n0 + row;
            if (nn < N) lab[(size_t)nn * T_OUT + j] = Lsf[row + T_WIN + j] - llv[row];
        }

        // pack 22 A-fragments (parity arrays: 4B-aligned b32 reads)
        const short* abase = ((lr & 1) ? Lbf1 : Lbf0) + rw + (lr & ~1);
        short8 af[11][2];
        #pragma unroll
        for (int kt = 0; kt < 11; ++kt) {
            #pragma unroll
            for (int mt = 0; mt < 2; ++mt) {
                const int* ip = (const int*)(abase + mt * 16 + kt * 32 + lq * 8);
                union { short8 s; int i[4]; } u;
                u.i[0] = ip[0]; u.i[1] = ip[1]; u.i[2] = ip[2]; u.i[3] = ip[3];
                af[kt][mt] = u.s;
            }
        }

        f32x4 zero4 = {0.f, 0.f, 0.f, 0.f};
        f32x4 acc2[2][3];
        #pragma unroll
        for (int mt = 0; mt < 2; ++mt)
            #pragma unroll
            for (int ct = 0; ct < 3; ++ct) acc2[mt][ct] = zero4;

        #pragma unroll 1
        for (int c = 0; c < 6; ++c) {
            __syncthreads();   // previous chunk's B1s/B2s/hs consumers done

            const char* g1 = (const char*)(W1F + (size_t)c * 11 * 4 * 512);
            for (int seg = wv; seg < 44; seg += 4) {
                __builtin_amdgcn_global_load_lds(
                    (const __attribute__((address_space(1))) unsigned int*)(g1 + seg * 1024 + lane * 16),
                    (__attribute__((address_space(3))) unsigned int*)((char*)B1s + seg * 1024),
                    16, 0, 0);
            }
            const char* g2 = (const char*)(W2F + (size_t)c * 6 * 512);
            for (int seg = wv; seg < 6; seg += 4) {
                __builtin_amdgcn_global_load_lds(
                    (const __attribute__((address_space(1))) unsigned int*)(g2 + seg * 1024 + lane * 16),
                    (__attribute__((address_space(3))) unsigned int*)((char*)B2s + seg * 1024),
                    16, 0, 0);
            }
            float b1v[4], csv[4];
            #pragma unroll
            for (int ct = 0; ct < 4; ++ct) {
                int col = c * 64 + ct * 16 + lr;
                b1v[ct] = (col < T_WIN) ? b1[col] : 0.f;
                csv[ct] = (col < T_WIN) ? cs[col] : 0.f;
            }
            __syncthreads();   // staging visible (vmcnt drained)

            f32x4 acc1[2][4];
            #pragma unroll
            for (int mt = 0; mt < 2; ++mt)
                #pragma unroll
                for (int ct = 0; ct < 4; ++ct) acc1[mt][ct] = zero4;

            #pragma unroll
            for (int kt = 0; kt < 11; ++kt) {
                #pragma unroll
                for (int ct = 0; ct < 4; ++ct) {
                    short8 bf = *(const short8*)&B1s[((kt * 4 + ct) * 64 + lane) * 8];
                    acc1[0][ct] = __builtin_amdgcn_mfma_f32_16x16x32_bf16(af[kt][0], bf, acc1[0][ct], 0, 0, 0);
                    acc1[1][ct] = __builtin_amdgcn_mfma_f32_16x16x32_bf16(af[kt][1], bf, acc1[1][ct], 0, 0, 0);
                }
            }

            // epilogue -> hs (wave-local rows; no extra barrier)
            #pragma unroll
            for (int mt = 0; mt < 2; ++mt)
                #pragma unroll
                for (int ct = 0; ct < 4; ++ct)
                    #pragma unroll
                    for (int r = 0; r < 4; ++r) {
                        int row = rw + mt * 16 + lq * 4 + r;
                        float pre = acc1[mt][ct][r] + b1v[ct] - llv[row] * csv[ct];
                        float e = __expf(2.f * pre);
                        float h = 1.f - 2.f * __builtin_amdgcn_rcpf(e + 1.f);
                        hs[row * 72 + ct * 16 + lr] = f2bf(h);
                    }

            #pragma unroll
            for (int kt2 = 0; kt2 < 2; ++kt2) {
                short8 a2[2];
                #pragma unroll
                for (int mt = 0; mt < 2; ++mt)
                    a2[mt] = *(const short8*)&hs[(rw + mt * 16 + lr) * 72 + kt2 * 32 + lq * 8];
                #pragma unroll
                for (int ct2 = 0; ct2 < 3; ++ct2) {
                    short8 bf2 = *(const short8*)&B2s[((kt2 * 3 + ct2) * 64 + lane) * 8];
                    acc2[0][ct2] = __builtin_amdgcn_mfma_f32_16x16x32_bf16(a2[0], bf2, acc2[0][ct2], 0, 0, 0);
                    acc2[1][ct2] = __builtin_amdgcn_mfma_f32_16x16x32_bf16(a2[1], bf2, acc2[1][ct2], 0, 0, 0);
                }
            }
        }

        float b2v[3];
        #pragma unroll
        for (int ct2 = 0; ct2 < 3; ++ct2) b2v[ct2] = b2[ct2 * 16 + lr];
        #pragma unroll
        for (int mt = 0; mt < 2; ++mt)
            #pragma unroll
            for (int ct2 = 0; ct2 < 3; ++ct2)
                #pragma unroll
                for (int r = 0; r < 4; ++r) {
                    int row = n0 + rw + mt * 16 + lq * 4 + r;
                    if (row < N)
                        outp[(size_t)row * T_OUT + ct2 * 16 + lr] = acc2[mt][ct2][r] + b2v[ct2];
                }
    }
}

__global__ __launch_bounds__(128) void loss2_kernel(
    const float* __restrict__ part, const int* __restrict__ lvp,
    float* __restrict__ out_loss, int T)
{
    __shared__ float red[128];
    red[threadIdx.x] = part[threadIdx.x];
    __syncthreads();
    for (int w = 64; w > 0; w >>= 1) {
        if (threadIdx.x < (unsigned)w) red[threadIdx.x] += red[threadIdx.x + w];
        __syncthreads();
    }
    if (threadIdx.x == 0) out_loss[0] = red[0] * (float)lvp[0] / (float)(T - 2);
}

extern "C" void kernel_launch(void* const* d_in, const int* in_sizes, int n_in,
                              void* d_out, int out_size, void* d_ws, size_t ws_size,
                              hipStream_t stream) {
    const float* x    = (const float*)d_in[0];
    const float* lvlc = (const float*)d_in[1];
    const float* seac = (const float*)d_in[2];
    const float* sp   = (const float*)d_in[3];
    const float* W1   = (const float*)d_in[4];
    const float* b1   = (const float*)d_in[5];
    const float* W2   = (const float*)d_in[6];
    const float* b2   = (const float*)d_in[7];
    const int*   lvp  = (const int*)d_in[10];

    int T = in_sizes[0];
    int N = T - T_WIN - T_OUT + 1;
    int NB = (N + BM - 1) / BM;

    short* W1F    = (short*)d_ws;                  // 264*512 shorts
    short* W2F    = W1F + 264 * 512;               // 36*512 shorts
    float* w_all  = (float*)(W2F + 36 * 512);      // T + 192
    float* levels = w_all + T + 192;               // T
    float* cs     = levels + T;                    // 352
    float* lpart  = cs + 352;                      // 128
    int*   flagsp = (int*)(lpart + 128);           // 4 flags on separate 128B lines

    float* outp  = (float*)d_out;
    float* lab   = outp + (size_t)N * T_OUT;
    float* lossp = lab + (size_t)N * T_OUT;

    init_flags<<<1, 64, 0, stream>>>(flagsp);
    fused_kernel<<<512, 256, 0, stream>>>(x, lvlc, seac, sp, W1, W2, b1, b2,
                                          W1F, W2F, w_all, levels, cs,
                                          outp, lab, lpart, flagsp, T, N, NB);
    loss2_kernel<<<1, 128, 0, stream>>>(lpart, lvp, lossp, T);
}